// Round 1
// baseline (2646.367 us; speedup 1.0000x reference)
//
#include <hip/hip_runtime.h>
#include <hip/hip_bf16.h>

typedef short short8 __attribute__((ext_vector_type(8)));
typedef float f32x4 __attribute__((ext_vector_type(4)));

#define H 512
#define BATCH 64
#define SEQ 256
#define NROWS 16384   // BATCH*SEQ
#define SCAN_WGS 32

__device__ __forceinline__ float bf2f(unsigned short u) {
    union { unsigned int i; float f; } v;
    v.i = ((unsigned int)u) << 16;
    return v.f;
}
__device__ __forceinline__ unsigned short f2bf(float f) {
    union { float f; unsigned int i; } v;
    v.f = f;
    unsigned int lsb = (v.i >> 16) & 1u;
    v.i += 0x7fffu + lsb;   // round-to-nearest-even
    return (unsigned short)(v.i >> 16);
}
__device__ __forceinline__ float sigm(float x) { return 1.f / (1.f + __expf(-x)); }
__device__ __forceinline__ float tanh_fast(float x) { return 2.f / (1.f + __expf(-2.f * x)) - 1.f; }

// ---------------------------------------------------------------------------
// convert + init kernel: x->bf16, Wl->bf16, W_ih->bf16, hidden->h_buf0, zero barrier
// ---------------------------------------------------------------------------
__global__ __launch_bounds__(256) void cvt_init(
    const float* __restrict__ x, const float* __restrict__ Wl,
    const float* __restrict__ Wih, const float* __restrict__ hid,
    unsigned short* __restrict__ actA, unsigned short* __restrict__ wlb,
    unsigned short* __restrict__ wihb, unsigned short* __restrict__ hbuf,
    unsigned int* __restrict__ bar)
{
    long idx4 = (long)blockIdx.x * 256 + threadIdx.x;
    if (idx4 == 0) { bar[0] = 0u; bar[1] = 0u; }
    long i = idx4 * 4;
    const long N1 = 8388608;            // x: 16384*512
    const long N2 = N1 + 1048576;       // Wl: 4*512*512
    const long N3 = N2 + 786432;        // W_ih: 1536*512
    const long N4 = N3 + 32768;         // hidden: 64*512
    const float* src; unsigned short* dst; long off;
    if (i < N1)      { src = x;   dst = actA; off = i; }
    else if (i < N2) { src = Wl;  dst = wlb;  off = i - N1; }
    else if (i < N3) { src = Wih; dst = wihb; off = i - N2; }
    else if (i < N4) { src = hid; dst = hbuf; off = i - N3; }
    else return;
    float4 v = *(const float4*)(src + off);
    ushort4 o;
    o.x = f2bf(v.x); o.y = f2bf(v.y); o.z = f2bf(v.z); o.w = f2bf(v.w);
    *(ushort4*)(dst + off) = o;
}

// ---------------------------------------------------------------------------
// GEMM: C[M,N] = A[M,K](bf16) * Bw[N,K]^T(bf16) + bias[N]
// 128x128 tile, 4 waves, BK=64, global_load_lds + XOR swizzle
// ---------------------------------------------------------------------------
template <int BF16OUT>
__global__ __launch_bounds__(256) void gemm_bt(
    const unsigned short* __restrict__ A, const unsigned short* __restrict__ Bw,
    const float* __restrict__ bias, void* __restrict__ Cout,
    int M, int N, int K)
{
    __shared__ unsigned short ldsA[128 * 64];
    __shared__ unsigned short ldsB[128 * 64];
    const int tid = threadIdx.x;
    const int lane = tid & 63;
    const int w = tid >> 6;
    const int nbx = N >> 7;
    const int bm = blockIdx.x / nbx;
    const int bn = blockIdx.x % nbx;
    const long m0 = (long)bm * 128;
    const long n0 = (long)bn * 128;
    const long Kb = (long)K * 2;   // row stride in bytes

    f32x4 acc[4][4];
#pragma unroll
    for (int i = 0; i < 4; ++i)
#pragma unroll
        for (int j = 0; j < 4; ++j) acc[i][j] = (f32x4){0.f, 0.f, 0.f, 0.f};

    for (int kt = 0; kt < K; kt += 64) {
        __syncthreads();   // protect LDS reuse (drains prior reads)
#pragma unroll
        for (int i = 0; i < 4; ++i) {
            int o   = (i * 256 + tid) * 16;       // byte offset inside tile
            int row = o >> 7;                     // 128B per row (64 bf16)
            int ch  = (o & 127) >> 4;             // 16B chunk index 0..7
            long gcol = (long)kt * 2 + (long)((ch ^ (row & 7)) << 4); // pre-swizzled source
            int ldsoff = (i * 256 + w * 64) * 8;  // wave-uniform base (ushort units)
            __builtin_amdgcn_global_load_lds(
                (const unsigned int*)((const char*)A + (m0 + row) * Kb + gcol),
                (unsigned int*)(ldsA + ldsoff), 16, 0, 0);
            __builtin_amdgcn_global_load_lds(
                (const unsigned int*)((const char*)Bw + (n0 + row) * Kb + gcol),
                (unsigned int*)(ldsB + ldsoff), 16, 0, 0);
        }
        __syncthreads();   // drains vmcnt before barrier (compiler-inserted)

#pragma unroll
        for (int k2 = 0; k2 < 2; ++k2) {
            short8 af[4], bfr[4];
#pragma unroll
            for (int i = 0; i < 4; ++i) {
                int row = (w >> 1) * 64 + i * 16 + (lane & 15);
                int byteo = (row * 128 + k2 * 64 + ((lane >> 4) * 16)) ^ ((row & 7) << 4);
                af[i] = *(const short8*)((const char*)ldsA + byteo);
            }
#pragma unroll
            for (int j = 0; j < 4; ++j) {
                int row = (w & 1) * 64 + j * 16 + (lane & 15);
                int byteo = (row * 128 + k2 * 64 + ((lane >> 4) * 16)) ^ ((row & 7) << 4);
                bfr[j] = *(const short8*)((const char*)ldsB + byteo);
            }
#pragma unroll
            for (int i = 0; i < 4; ++i)
#pragma unroll
                for (int j = 0; j < 4; ++j)
                    acc[i][j] = __builtin_amdgcn_mfma_f32_16x16x32_bf16(af[i], bfr[j], acc[i][j], 0, 0, 0);
        }
    }

    // epilogue: C row = (lane>>4)*4 + r, col = lane&15  (within each 16x16 frag)
#pragma unroll
    for (int j = 0; j < 4; ++j) {
        long n = n0 + (w & 1) * 64 + j * 16 + (lane & 15);
        float bz = bias ? bias[n] : 0.f;
#pragma unroll
        for (int i = 0; i < 4; ++i) {
#pragma unroll
            for (int r = 0; r < 4; ++r) {
                long m = m0 + (w >> 1) * 64 + i * 16 + (lane >> 4) * 4 + r;
                float v = acc[i][j][r] + bz;
                if (BF16OUT) ((unsigned short*)Cout)[m * N + n] = f2bf(v);
                else         ((float*)Cout)[m * N + n] = v;
            }
        }
    }
}

// ---------------------------------------------------------------------------
// LayerNorm + ReLU: reads f32 [rows,512], writes bf16. One wave per row.
// ---------------------------------------------------------------------------
__global__ __launch_bounds__(256) void ln_relu(
    const float* __restrict__ X, const float* __restrict__ g,
    const float* __restrict__ b, unsigned short* __restrict__ Y)
{
    const int w = threadIdx.x >> 6;
    const int lane = threadIdx.x & 63;
    const long row = (long)blockIdx.x * 4 + w;
    const float* xr = X + row * H;
    float4 v0 = *(const float4*)(xr + lane * 4);
    float4 v1 = *(const float4*)(xr + 256 + lane * 4);
    float s = v0.x + v0.y + v0.z + v0.w + v1.x + v1.y + v1.z + v1.w;
    float q = v0.x * v0.x + v0.y * v0.y + v0.z * v0.z + v0.w * v0.w
            + v1.x * v1.x + v1.y * v1.y + v1.z * v1.z + v1.w * v1.w;
#pragma unroll
    for (int off = 1; off < 64; off <<= 1) {
        s += __shfl_xor(s, off);
        q += __shfl_xor(q, off);
    }
    float mu = s * (1.f / 512.f);
    float var = q * (1.f / 512.f) - mu * mu;
    float rs = rsqrtf(var + 1e-5f);
    int c0 = lane * 4;
    float4 ga = *(const float4*)(g + c0);
    float4 ba = *(const float4*)(b + c0);
    float4 gb = *(const float4*)(g + 256 + c0);
    float4 bb = *(const float4*)(b + 256 + c0);
    ushort4 o0, o1;
    o0.x = f2bf(fmaxf(0.f, (v0.x - mu) * rs * ga.x + ba.x));
    o0.y = f2bf(fmaxf(0.f, (v0.y - mu) * rs * ga.y + ba.y));
    o0.z = f2bf(fmaxf(0.f, (v0.z - mu) * rs * ga.z + ba.z));
    o0.w = f2bf(fmaxf(0.f, (v0.w - mu) * rs * ga.w + ba.w));
    o1.x = f2bf(fmaxf(0.f, (v1.x - mu) * rs * gb.x + bb.x));
    o1.y = f2bf(fmaxf(0.f, (v1.y - mu) * rs * gb.y + bb.y));
    o1.z = f2bf(fmaxf(0.f, (v1.z - mu) * rs * gb.z + bb.z));
    o1.w = f2bf(fmaxf(0.f, (v1.w - mu) * rs * gb.w + bb.w));
    *(ushort4*)(Y + row * H + c0) = o0;
    *(ushort4*)(Y + row * H + 256 + c0) = o1;
}

// ---------------------------------------------------------------------------
// Grid barrier (agent scope, epoch-based). Requires all blocks co-resident.
// ---------------------------------------------------------------------------
__device__ __forceinline__ void grid_barrier(unsigned int* bar, unsigned int nb, unsigned int epoch) {
    __syncthreads();
    if (threadIdx.x == 0) {
        unsigned int prev = __hip_atomic_fetch_add(&bar[0], 1u, __ATOMIC_ACQ_REL, __HIP_MEMORY_SCOPE_AGENT);
        if (prev == (epoch + 1u) * nb - 1u) {
            __hip_atomic_store(&bar[1], epoch + 1u, __ATOMIC_RELEASE, __HIP_MEMORY_SCOPE_AGENT);
        } else {
            unsigned int v;
            do {
                __builtin_amdgcn_s_sleep(2);
                v = __hip_atomic_load(&bar[1], __ATOMIC_ACQUIRE, __HIP_MEMORY_SCOPE_AGENT);
            } while (v <= epoch);
        }
    }
    __syncthreads();
}

// ---------------------------------------------------------------------------
// GRU scan: 32 persistent workgroups, each owns 16 hidden units (48 W_hh rows
// in swizzled LDS). One grid barrier per timestep; double-buffered h (bf16).
// gh = h_eff @ W_hh_slice^T via MFMA (M=64 batch, N=48, K=512).
// ---------------------------------------------------------------------------
__global__ __launch_bounds__(256) void gru_scan(
    const unsigned short* __restrict__ gi,   // [B*S, 1536] bf16 (b_ih already added)
    const float* __restrict__ Whh,           // [1536, 512] f32
    const float* __restrict__ bhh,           // [1536] f32
    const int* __restrict__ dones,           // [B, S] int
    unsigned short* __restrict__ hbuf,       // 2 x [64*512] bf16
    unsigned short* __restrict__ rnn,        // [B*S, 512] bf16
    float* __restrict__ hid_out,             // [64, 512] f32 (d_out)
    unsigned int* __restrict__ bar)
{
    __shared__ unsigned short ldsW[48 * 512];   // 48KB, XOR-swizzled
    const int tid = threadIdx.x;
    const int lane = tid & 63;
    const int w = tid >> 6;
    const int j0 = blockIdx.x * 16;

    // stage W_hh slice (rows: [r j0..j0+15][z ...][n ...]) f32 -> bf16 swizzled
    for (int e = tid; e < 48 * 512; e += 256) {
        int rrow = e >> 9;
        int col = e & 511;
        int gate = rrow >> 4;
        int jl = rrow & 15;
        float v = Whh[((long)(gate * 512 + j0 + jl)) * 512 + col];
        int byteo = (rrow * 1024 + col * 2) ^ ((rrow & 7) << 4);
        *(unsigned short*)((char*)ldsW + byteo) = f2bf(v);
    }

    const int jl = lane & 15;
    const int j = j0 + jl;
    const float bhr = bhh[j];
    const float bhz = bhh[512 + j];
    const float bhn = bhh[1024 + j];
    const int bA = w * 16 + (lane & 15);   // A-operand batch row for this lane
    __syncthreads();

    for (int s = 0; s < SEQ; ++s) {
        const unsigned short* hprev = hbuf + (s & 1) * (BATCH * H);
        unsigned short* hnext = hbuf + ((s + 1) & 1) * (BATCH * H);

        const bool dA = (dones[bA * SEQ + s] != 0);
        f32x4 acch[3];
#pragma unroll
        for (int g = 0; g < 3; ++g) acch[g] = (f32x4){0.f, 0.f, 0.f, 0.f};

        const unsigned short* hrowA = hprev + bA * H + ((lane >> 4) * 8);
#pragma unroll
        for (int kk = 0; kk < 16; ++kk) {
            short8 ah;
            if (dA) ah = (short8){0, 0, 0, 0, 0, 0, 0, 0};
            else    ah = *(const short8*)(hrowA + kk * 32);
#pragma unroll
            for (int g = 0; g < 3; ++g) {
                int rrow = g * 16 + (lane & 15);
                int byteo = (rrow * 1024 + kk * 64 + ((lane >> 4) * 16)) ^ ((rrow & 7) << 4);
                short8 bfrag = *(const short8*)((const char*)ldsW + byteo);
                acch[g] = __builtin_amdgcn_mfma_f32_16x16x32_bf16(ah, bfrag, acch[g], 0, 0, 0);
            }
        }

        // epilogue: lane holds output rows b = w*16 + (lane>>4)*4 + r, col j
#pragma unroll
        for (int r = 0; r < 4; ++r) {
            int b = w * 16 + (lane >> 4) * 4 + r;
            long gib = ((long)(b * SEQ + s)) * 1536 + j;
            float ix = bf2f(gi[gib]);            // i_r (includes b_ih)
            float iz = bf2f(gi[gib + 512]);      // i_z
            float inn = bf2f(gi[gib + 1024]);    // i_n
            bool dn = (dones[b * SEQ + s] != 0);
            float heff = dn ? 0.f : bf2f(hprev[b * H + j]);
            float rg = sigm(ix + acch[0][r] + bhr);
            float zg = sigm(iz + acch[1][r] + bhz);
            float ng = tanh_fast(inn + rg * (acch[2][r] + bhn));
            float hnew = (1.f - zg) * ng + zg * heff;
            unsigned short hb = f2bf(hnew);
            hnext[b * H + j] = hb;
            rnn[((long)(b * SEQ + s)) * H + j] = hb;
            if (s == SEQ - 1) hid_out[b * H + j] = hnew;
        }
        grid_barrier(bar, SCAN_WGS, (unsigned int)s);
    }
}

// ---------------------------------------------------------------------------
// Q head: q[row,a] = rnn[row,:] . Wq[a,:] + bq[a], minus unavailability mask.
// One wave per row; lane = (a, k-chunk).
// ---------------------------------------------------------------------------
__global__ __launch_bounds__(256) void qhead(
    const unsigned short* __restrict__ rnn, const float* __restrict__ Wq,
    const float* __restrict__ bq, const int* __restrict__ avail,
    float* __restrict__ qout)
{
    const int w = threadIdx.x >> 6;
    const int lane = threadIdx.x & 63;
    const long row = (long)blockIdx.x * 4 + w;
    const int a = lane & 15;
    const int kc = lane >> 4;
    const unsigned short* hr = rnn + row * H + kc * 128;
    const float* wr = Wq + a * H + kc * 128;
    float sum = 0.f;
#pragma unroll
    for (int i = 0; i < 128; i += 8) {
        short8 hv = *(const short8*)(hr + i);
        float4 wa = *(const float4*)(wr + i);
        float4 wb = *(const float4*)(wr + i + 4);
        sum += bf2f((unsigned short)hv[0]) * wa.x;
        sum += bf2f((unsigned short)hv[1]) * wa.y;
        sum += bf2f((unsigned short)hv[2]) * wa.z;
        sum += bf2f((unsigned short)hv[3]) * wa.w;
        sum += bf2f((unsigned short)hv[4]) * wb.x;
        sum += bf2f((unsigned short)hv[5]) * wb.y;
        sum += bf2f((unsigned short)hv[6]) * wb.z;
        sum += bf2f((unsigned short)hv[7]) * wb.w;
    }
    sum += __shfl_xor(sum, 16);
    sum += __shfl_xor(sum, 32);
    if (kc == 0) {
        float qv = sum + bq[a];
        int av = avail[row * 16 + a];
        if (av == 0) qv -= 1e10f;
        qout[row * 16 + a] = qv;
    }
}

// ---------------------------------------------------------------------------
extern "C" void kernel_launch(void* const* d_in, const int* in_sizes, int n_in,
                              void* d_out, int out_size, void* d_ws, size_t ws_size,
                              hipStream_t stream)
{
    const float* hidden = (const float*)d_in[0];
    const float* x      = (const float*)d_in[1];
    const int*   dones  = (const int*)d_in[2];
    const int*   avail  = (const int*)d_in[3];
    const float* Wl     = (const float*)d_in[4];
    const float* bl     = (const float*)d_in[5];
    const float* ln_g   = (const float*)d_in[6];
    const float* ln_b   = (const float*)d_in[7];
    const float* W_ih   = (const float*)d_in[8];
    const float* W_hh   = (const float*)d_in[9];
    const float* b_ih   = (const float*)d_in[10];
    const float* b_hh   = (const float*)d_in[11];
    const float* Wq     = (const float*)d_in[12];
    const float* bq     = (const float*)d_in[13];

    char* p = (char*)d_ws;
    unsigned short* actA = (unsigned short*)p; p += (size_t)NROWS * H * 2;      // 16 MB
    unsigned short* actB = (unsigned short*)p;                                   // gi overlays actB+gout
    unsigned short* gi   = actB;                                                 // [NROWS,1536] bf16 = 48 MB
    p += (size_t)NROWS * H * 2;                                                  // 16 MB
    float* gout = (float*)p; p += (size_t)NROWS * H * 4;                         // 32 MB
    unsigned short* rnn  = (unsigned short*)p; p += (size_t)NROWS * H * 2;       // 16 MB
    unsigned short* wlb  = (unsigned short*)p; p += (size_t)4 * H * H * 2;       // 2 MB
    unsigned short* wihb = (unsigned short*)p; p += (size_t)3 * H * H * 2;       // 1.5 MB
    unsigned short* hbuf = (unsigned short*)p; p += (size_t)2 * BATCH * H * 2;   // 256 KB
    unsigned int* bar    = (unsigned int*)p;   p += 256;

    // 1) convert inputs to bf16, init h buffer + barrier state
    cvt_init<<<10016, 256, 0, stream>>>(x, Wl, W_ih, hidden, actA, wlb, wihb, hbuf, bar);

    // 2) MLP stack: 4 x (GEMM f32-out + bias, then LN+ReLU -> bf16)
    unsigned short* cur = actA;
    unsigned short* nxt = actB;
    for (int l = 0; l < 4; ++l) {
        gemm_bt<0><<<512, 256, 0, stream>>>(cur, wlb + (size_t)l * H * H, bl + l * H,
                                            (void*)gout, NROWS, H, H);
        ln_relu<<<4096, 256, 0, stream>>>(gout, ln_g + l * H, ln_b + l * H, nxt);
        unsigned short* t = cur; cur = nxt; nxt = t;
    }
    // after 4 layers, activations are in actA (cur == actA)

    // 3) gi = act @ W_ih^T + b_ih  -> bf16 [NROWS, 1536] (overlays actB+gout)
    gemm_bt<1><<<1536, 256, 0, stream>>>(cur, wihb, b_ih, (void*)gi, NROWS, 3 * H, H);

    // 4) GRU scan (persistent, 32 WGs, one grid barrier per step)
    gru_scan<<<SCAN_WGS, 256, 0, stream>>>(gi, W_hh, b_hh, dones, hbuf, rnn,
                                           (float*)d_out, bar);

    // 5) Q head + availability mask
    qhead<<<4096, 256, 0, stream>>>(rnn, Wq, bq, avail, (float*)d_out + BATCH * H);
}

// Round 2
// 891.828 us; speedup vs baseline: 2.9674x; 2.9674x over previous
//
#include <hip/hip_runtime.h>
#include <hip/hip_bf16.h>

typedef short short8 __attribute__((ext_vector_type(8)));
typedef float f32x4 __attribute__((ext_vector_type(4)));

#define H 512
#define BATCH 64
#define SEQ 256
#define NROWS 16384   // BATCH*SEQ
#define RG 7          // row-groups in scan grid (224 WGs = 32 jg * 7 rg)

__device__ __forceinline__ float bf2f(unsigned short u) {
    union { unsigned int i; float f; } v;
    v.i = ((unsigned int)u) << 16;
    return v.f;
}
__device__ __forceinline__ unsigned short f2bf(float f) {
    union { float f; unsigned int i; } v;
    v.f = f;
    unsigned int lsb = (v.i >> 16) & 1u;
    v.i += 0x7fffu + lsb;   // round-to-nearest-even
    return (unsigned short)(v.i >> 16);
}
__device__ __forceinline__ float sigm(float x) { return 1.f / (1.f + __expf(-x)); }
__device__ __forceinline__ float tanh_fast(float x) { return 2.f / (1.f + __expf(-2.f * x)) - 1.f; }

// ---------------------------------------------------------------------------
// convert + init: x->bf16, Wl->bf16, W_ih->bf16; zero meta (hist/offs/M/barrier)
// ---------------------------------------------------------------------------
__global__ __launch_bounds__(256) void cvt_init(
    const float* __restrict__ x, const float* __restrict__ Wl,
    const float* __restrict__ Wih,
    unsigned short* __restrict__ actA, unsigned short* __restrict__ wlb,
    unsigned short* __restrict__ wihb, unsigned int* __restrict__ meta)
{
    long idx4 = (long)blockIdx.x * 256 + threadIdx.x;
    if (idx4 < 1024) meta[idx4] = 0u;
    long i = idx4 * 4;
    const long N1 = 8388608;            // x: 16384*512
    const long N2 = N1 + 1048576;       // Wl: 4*512*512
    const long N3 = N2 + 786432;        // W_ih: 1536*512
    const float* src; unsigned short* dst; long off;
    if (i < N1)      { src = x;   dst = actA; off = i; }
    else if (i < N2) { src = Wl;  dst = wlb;  off = i - N1; }
    else if (i < N3) { src = Wih; dst = wihb; off = i - N2; }
    else return;
    float4 v = *(const float4*)(src + off);
    ushort4 o;
    o.x = f2bf(v.x); o.y = f2bf(v.y); o.z = f2bf(v.z); o.w = f2bf(v.w);
    *(ushort4*)(dst + off) = o;
}

// ---------------------------------------------------------------------------
// Segment machinery. Segment = maximal run starting at s where (s==0 || done[b,s]).
// ---------------------------------------------------------------------------
__global__ __launch_bounds__(256) void seg_build(
    const int* __restrict__ dones, int* __restrict__ lenArr,
    unsigned int* __restrict__ hist)
{
    __shared__ int d[256];
    const int b = blockIdx.x, s = threadIdx.x;
    d[s] = dones[b * 256 + s];
    __syncthreads();
    int len = 0;
    bool start = (s == 0) || (d[s] != 0);
    if (start) {
        len = 1;
        while (s + len < 256 && d[s + len] == 0) len++;
        atomicAdd(&hist[len], 1u);
    }
    lenArr[b * 256 + s] = len;
}

// M[t] = #segments with len > t (suffix sums); offs[L] = M[L] (scatter cursors)
__global__ __launch_bounds__(256) void seg_offsets(
    const unsigned int* __restrict__ hist, int* __restrict__ Marr,
    unsigned int* __restrict__ offs)
{
    __shared__ unsigned int h[257];
    const int t = threadIdx.x;
    h[t] = hist[t];
    if (t == 0) h[256] = hist[256];
    __syncthreads();
    for (int tt = t; tt <= 256; tt += 256) {
        unsigned int m = 0;
        for (int L = tt + 1; L <= 256; ++L) m += h[L];
        Marr[tt] = (int)m;
        offs[tt] = m;
    }
}

// counting-sort scatter: rows sorted by length descending -> alive set is prefix
__global__ __launch_bounds__(256) void seg_scatter(
    const int* __restrict__ lenArr, unsigned int* __restrict__ offs,
    int* __restrict__ recs)
{
    const int b = blockIdx.x, s = threadIdx.x;
    int len = lenArr[b * 256 + s];
    if (len > 0) {
        unsigned int pos = atomicAdd(&offs[len], 1u);
        recs[pos] = (b << 16) | s;
    }
}

// h_state row init: hidden[b] for the s==0 segment when !done[b,0], else 0.
__global__ __launch_bounds__(256) void h_init(
    const int* __restrict__ recs, const int* __restrict__ Marr,
    const int* __restrict__ dones, const float* __restrict__ hidden,
    unsigned short* __restrict__ hst)
{
    const int w = threadIdx.x >> 6, lane = threadIdx.x & 63;
    const int i = blockIdx.x * 4 + w;
    const int nseg = Marr[0];
    const int c0 = lane * 8;
    unsigned short* dst = hst + (long)i * 512 + c0;
    if (i < nseg) {
        int rec = recs[i];
        int b = rec >> 16, st = rec & 0xffff;
        if (st == 0 && dones[b * 256] == 0) {
            float4 va = *(const float4*)(hidden + b * 512 + c0);
            float4 vb = *(const float4*)(hidden + b * 512 + c0 + 4);
            ushort4 o0 = {f2bf(va.x), f2bf(va.y), f2bf(va.z), f2bf(va.w)};
            ushort4 o1 = {f2bf(vb.x), f2bf(vb.y), f2bf(vb.z), f2bf(vb.w)};
            *(ushort4*)dst = o0; *(ushort4*)(dst + 4) = o1;
            return;
        }
    }
    ushort4 z4 = {0, 0, 0, 0};
    *(ushort4*)dst = z4; *(ushort4*)(dst + 4) = z4;
}

// ---------------------------------------------------------------------------
// GEMM: C[M,N] = A[M,K](bf16) * Bw[N,K]^T(bf16) + bias[N]   (unchanged r1)
// ---------------------------------------------------------------------------
template <int BF16OUT>
__global__ __launch_bounds__(256) void gemm_bt(
    const unsigned short* __restrict__ A, const unsigned short* __restrict__ Bw,
    const float* __restrict__ bias, void* __restrict__ Cout,
    int M, int N, int K)
{
    __shared__ unsigned short ldsA[128 * 64];
    __shared__ unsigned short ldsB[128 * 64];
    const int tid = threadIdx.x;
    const int lane = tid & 63;
    const int w = tid >> 6;
    const int nbx = N >> 7;
    const int bm = blockIdx.x / nbx;
    const int bn = blockIdx.x % nbx;
    const long m0 = (long)bm * 128;
    const long n0 = (long)bn * 128;
    const long Kb = (long)K * 2;

    f32x4 acc[4][4];
#pragma unroll
    for (int i = 0; i < 4; ++i)
#pragma unroll
        for (int j = 0; j < 4; ++j) acc[i][j] = (f32x4){0.f, 0.f, 0.f, 0.f};

    for (int kt = 0; kt < K; kt += 64) {
        __syncthreads();
#pragma unroll
        for (int i = 0; i < 4; ++i) {
            int o   = (i * 256 + tid) * 16;
            int row = o >> 7;
            int ch  = (o & 127) >> 4;
            long gcol = (long)kt * 2 + (long)((ch ^ (row & 7)) << 4);
            int ldsoff = (i * 256 + w * 64) * 8;
            __builtin_amdgcn_global_load_lds(
                (const unsigned int*)((const char*)A + (m0 + row) * Kb + gcol),
                (unsigned int*)(ldsA + ldsoff), 16, 0, 0);
            __builtin_amdgcn_global_load_lds(
                (const unsigned int*)((const char*)Bw + (n0 + row) * Kb + gcol),
                (unsigned int*)(ldsB + ldsoff), 16, 0, 0);
        }
        __syncthreads();

#pragma unroll
        for (int k2 = 0; k2 < 2; ++k2) {
            short8 af[4], bfr[4];
#pragma unroll
            for (int i = 0; i < 4; ++i) {
                int row = (w >> 1) * 64 + i * 16 + (lane & 15);
                int byteo = (row * 128 + k2 * 64 + ((lane >> 4) * 16)) ^ ((row & 7) << 4);
                af[i] = *(const short8*)((const char*)ldsA + byteo);
            }
#pragma unroll
            for (int j = 0; j < 4; ++j) {
                int row = (w & 1) * 64 + j * 16 + (lane & 15);
                int byteo = (row * 128 + k2 * 64 + ((lane >> 4) * 16)) ^ ((row & 7) << 4);
                bfr[j] = *(const short8*)((const char*)ldsB + byteo);
            }
#pragma unroll
            for (int i = 0; i < 4; ++i)
#pragma unroll
                for (int j = 0; j < 4; ++j)
                    acc[i][j] = __builtin_amdgcn_mfma_f32_16x16x32_bf16(af[i], bfr[j], acc[i][j], 0, 0, 0);
        }
    }

#pragma unroll
    for (int j = 0; j < 4; ++j) {
        long n = n0 + (w & 1) * 64 + j * 16 + (lane & 15);
        float bz = bias ? bias[n] : 0.f;
#pragma unroll
        for (int i = 0; i < 4; ++i) {
#pragma unroll
            for (int r = 0; r < 4; ++r) {
                long m = m0 + (w >> 1) * 64 + i * 16 + (lane >> 4) * 4 + r;
                float v = acc[i][j][r] + bz;
                if (BF16OUT) ((unsigned short*)Cout)[m * N + n] = f2bf(v);
                else         ((float*)Cout)[m * N + n] = v;
            }
        }
    }
}

// ---------------------------------------------------------------------------
// LayerNorm + ReLU (unchanged r1)
// ---------------------------------------------------------------------------
__global__ __launch_bounds__(256) void ln_relu(
    const float* __restrict__ X, const float* __restrict__ g,
    const float* __restrict__ b, unsigned short* __restrict__ Y)
{
    const int w = threadIdx.x >> 6;
    const int lane = threadIdx.x & 63;
    const long row = (long)blockIdx.x * 4 + w;
    const float* xr = X + row * H;
    float4 v0 = *(const float4*)(xr + lane * 4);
    float4 v1 = *(const float4*)(xr + 256 + lane * 4);
    float s = v0.x + v0.y + v0.z + v0.w + v1.x + v1.y + v1.z + v1.w;
    float q = v0.x * v0.x + v0.y * v0.y + v0.z * v0.z + v0.w * v0.w
            + v1.x * v1.x + v1.y * v1.y + v1.z * v1.z + v1.w * v1.w;
#pragma unroll
    for (int off = 1; off < 64; off <<= 1) {
        s += __shfl_xor(s, off);
        q += __shfl_xor(q, off);
    }
    float mu = s * (1.f / 512.f);
    float var = q * (1.f / 512.f) - mu * mu;
    float rs = rsqrtf(var + 1e-5f);
    int c0 = lane * 4;
    float4 ga = *(const float4*)(g + c0);
    float4 ba = *(const float4*)(b + c0);
    float4 gb = *(const float4*)(g + 256 + c0);
    float4 bb = *(const float4*)(b + 256 + c0);
    ushort4 o0, o1;
    o0.x = f2bf(fmaxf(0.f, (v0.x - mu) * rs * ga.x + ba.x));
    o0.y = f2bf(fmaxf(0.f, (v0.y - mu) * rs * ga.y + ba.y));
    o0.z = f2bf(fmaxf(0.f, (v0.z - mu) * rs * ga.z + ba.z));
    o0.w = f2bf(fmaxf(0.f, (v0.w - mu) * rs * ga.w + ba.w));
    o1.x = f2bf(fmaxf(0.f, (v1.x - mu) * rs * gb.x + bb.x));
    o1.y = f2bf(fmaxf(0.f, (v1.y - mu) * rs * gb.y + bb.y));
    o1.z = f2bf(fmaxf(0.f, (v1.z - mu) * rs * gb.z + bb.z));
    o1.w = f2bf(fmaxf(0.f, (v1.w - mu) * rs * gb.w + bb.w));
    *(ushort4*)(Y + row * H + c0) = o0;
    *(ushort4*)(Y + row * H + 256 + c0) = o1;
}

// ---------------------------------------------------------------------------
// 2-level grid barrier (RG groups of 32), epoch-based monotone counters.
// meta[0..RG): group counters; meta[7]: root; meta[8]: release flag.
// ---------------------------------------------------------------------------
__device__ __forceinline__ void gbar(unsigned int* __restrict__ meta,
                                     int gid, unsigned int epoch)
{
    __syncthreads();
    if (threadIdx.x == 0) {
        unsigned int p = __hip_atomic_fetch_add(&meta[gid], 1u, __ATOMIC_ACQ_REL,
                                                __HIP_MEMORY_SCOPE_AGENT);
        bool release = false;
        if (p == (epoch + 1u) * 32u - 1u) {
            unsigned int q = __hip_atomic_fetch_add(&meta[7], 1u, __ATOMIC_ACQ_REL,
                                                    __HIP_MEMORY_SCOPE_AGENT);
            if (q == (epoch + 1u) * (unsigned)RG - 1u) {
                __hip_atomic_store(&meta[8], epoch + 1u, __ATOMIC_RELEASE,
                                   __HIP_MEMORY_SCOPE_AGENT);
                release = true;
            }
        }
        if (!release) {
            while (__hip_atomic_load(&meta[8], __ATOMIC_ACQUIRE,
                                     __HIP_MEMORY_SCOPE_AGENT) <= epoch)
                __builtin_amdgcn_s_sleep(2);
        }
    }
    __syncthreads();
}

// ---------------------------------------------------------------------------
// Segment-parallel GRU scan. 224 persistent WGs = 32 jg (16 output cols each,
// 48x512 W_hh slice in swizzled LDS) x 7 rg (round-robin over 64-row tiles).
// Per local step t: GEMM [M_t,512]x[512,48] per jg + fused GRU pointwise,
// h ping-pongs between hstA/hstB; one grid barrier per t.
// ---------------------------------------------------------------------------
__global__ __launch_bounds__(256) void gru_seg_scan(
    const unsigned short* __restrict__ gi,   // [B*S,1536] bf16 (b_ih included)
    const float* __restrict__ Whh,           // [1536,512] f32
    const float* __restrict__ bhh,           // [1536] f32
    const int* __restrict__ Marr,            // alive-count per t
    const int* __restrict__ recs,            // sorted (b<<16)|start
    unsigned short* __restrict__ hstA,       // read when t even
    unsigned short* __restrict__ hstB,
    unsigned short* __restrict__ rnn,        // [B*S,512] bf16
    float* __restrict__ hid_out,             // [64,512] f32
    unsigned int* __restrict__ meta)
{
    __shared__ unsigned short ldsW[48 * 512];   // 48 KB
    __shared__ unsigned short ldsA[64 * 512];   // 64 KB
    const int tid = threadIdx.x;
    const int lane = tid & 63;
    const int w = tid >> 6;
    const int jg = blockIdx.x & 31;
    const int rg = blockIdx.x >> 5;     // 0..RG-1
    const int j0 = jg * 16;

    // stage W_hh slice (rows: r gate j0..j0+15, z, n), f32 -> bf16, XOR swizzle
    for (int e = tid; e < 48 * 512; e += 256) {
        int rrow = e >> 9;
        int col = e & 511;
        int gate = rrow >> 4;
        int jl = rrow & 15;
        float v = Whh[((long)(gate * 512 + j0 + jl)) * 512 + col];
        int byteo = (rrow * 1024 + col * 2) ^ ((rrow & 7) << 4);
        *(unsigned short*)((char*)ldsW + byteo) = f2bf(v);
    }

    const int j = j0 + (lane & 15);
    const float bhr = bhh[j];
    const float bhz = bhh[512 + j];
    const float bhn = bhh[1024 + j];

    for (int t = 0; t < 256; ++t) {
        const int Mt = Marr[t];
        if (Mt == 0) break;
        const unsigned short* hsrc = (t & 1) ? hstB : hstA;
        unsigned short* hdst = (t & 1) ? hstA : hstB;
        const int ntiles = (Mt + 63) >> 6;

        int tt = rg;
        int rec_c[4];
        if (tt < ntiles) {
#pragma unroll
            for (int q = 0; q < 4; ++q) {
                int rowg = tt * 64 + w * 16 + (lane >> 4) * 4 + q;
                rec_c[q] = (rowg < Mt) ? recs[rowg] : -1;
            }
        }

        for (; tt < ntiles; tt += RG) {
            const int r0 = tt * 64;
            __syncthreads();   // protect ldsA (and first-iter ldsW) before overwrite

            // issue A-tile stage: h_state rows [r0,r0+64) x 512, pre-swizzled src
#pragma unroll
            for (int i = 0; i < 16; ++i) {
                int o = (i * 256 + tid) * 16;      // tile-local byte offset
                int row = o >> 10;                 // 1024 B per row
                int ch = (o & 1023) >> 4;
                int sch = ch ^ (row & 7);
                const char* src = (const char*)hsrc + ((long)(r0 + row) * 512) * 2 + (sch << 4);
                __builtin_amdgcn_global_load_lds(
                    (const unsigned int*)src,
                    (unsigned int*)(ldsA + (i * 256 + w * 64) * 8), 16, 0, 0);
            }

            // issue gi loads for THIS tile (latency overlaps the stage drain)
            unsigned short g_r[4], g_z[4], g_n[4];
            int bq_[4], sq_[4];
#pragma unroll
            for (int q = 0; q < 4; ++q) {
                bq_[q] = -1; sq_[q] = -1;
                if (rec_c[q] >= 0) {
                    int b = rec_c[q] >> 16, st = rec_c[q] & 0xffff;
                    int s = st + t;
                    long gib = ((long)(b * 256 + s)) * 1536 + j;
                    g_r[q] = gi[gib];
                    g_z[q] = gi[gib + 512];
                    g_n[q] = gi[gib + 1024];
                    bq_[q] = b; sq_[q] = s;
                }
            }

            // prefetch recs for next tile
            int rec_n[4];
            const int tt2 = tt + RG;
            if (tt2 < ntiles) {
#pragma unroll
                for (int q = 0; q < 4; ++q) {
                    int rowg = tt2 * 64 + w * 16 + (lane >> 4) * 4 + q;
                    rec_n[q] = (rowg < Mt) ? recs[rowg] : -1;
                }
            }

            __syncthreads();   // A tile (and gi regs) ready

            f32x4 acch[3];
#pragma unroll
            for (int g = 0; g < 3; ++g) acch[g] = (f32x4){0.f, 0.f, 0.f, 0.f};

#pragma unroll
            for (int kk = 0; kk < 16; ++kk) {
                int arow = w * 16 + (lane & 15);
                int abyte = (arow * 1024 + kk * 64 + ((lane >> 4) * 16)) ^ ((arow & 7) << 4);
                short8 ah = *(const short8*)((const char*)ldsA + abyte);
#pragma unroll
                for (int g = 0; g < 3; ++g) {
                    int rrow = g * 16 + (lane & 15);
                    int bbyte = (rrow * 1024 + kk * 64 + ((lane >> 4) * 16)) ^ ((rrow & 7) << 4);
                    short8 bfrag = *(const short8*)((const char*)ldsW + bbyte);
                    acch[g] = __builtin_amdgcn_mfma_f32_16x16x32_bf16(ah, bfrag, acch[g], 0, 0, 0);
                }
            }

            // fused GRU pointwise + stores
#pragma unroll
            for (int q = 0; q < 4; ++q) {
                if (rec_c[q] >= 0) {
                    int rowl = w * 16 + (lane >> 4) * 4 + q;
                    int rowg = r0 + rowl;
                    int hby = (rowl * 1024 + j * 2) ^ ((rowl & 7) << 4);
                    float heff = bf2f(*(const unsigned short*)((const char*)ldsA + hby));
                    float rgt = sigm(bf2f(g_r[q]) + acch[0][q] + bhr);
                    float zgt = sigm(bf2f(g_z[q]) + acch[1][q] + bhz);
                    float ngt = tanh_fast(bf2f(g_n[q]) + rgt * (acch[2][q] + bhn));
                    float hnew = (1.f - zgt) * ngt + zgt * heff;
                    unsigned short hb = f2bf(hnew);
                    hdst[(long)rowg * 512 + j] = hb;
                    rnn[((long)(bq_[q] * 256 + sq_[q])) * 512 + j] = hb;
                    if (sq_[q] == 255) hid_out[bq_[q] * 512 + j] = hnew;
                }
            }
#pragma unroll
            for (int q = 0; q < 4; ++q) rec_c[q] = rec_n[q];
        }
        gbar(meta, rg, (unsigned int)t);
    }
}

// ---------------------------------------------------------------------------
// Q head (unchanged r1)
// ---------------------------------------------------------------------------
__global__ __launch_bounds__(256) void qhead(
    const unsigned short* __restrict__ rnn, const float* __restrict__ Wq,
    const float* __restrict__ bq, const int* __restrict__ avail,
    float* __restrict__ qout)
{
    const int w = threadIdx.x >> 6;
    const int lane = threadIdx.x & 63;
    const long row = (long)blockIdx.x * 4 + w;
    const int a = lane & 15;
    const int kc = lane >> 4;
    const unsigned short* hr = rnn + row * H + kc * 128;
    const float* wr = Wq + a * H + kc * 128;
    float sum = 0.f;
#pragma unroll
    for (int i = 0; i < 128; i += 8) {
        short8 hv = *(const short8*)(hr + i);
        float4 wa = *(const float4*)(wr + i);
        float4 wb = *(const float4*)(wr + i + 4);
        sum += bf2f((unsigned short)hv[0]) * wa.x;
        sum += bf2f((unsigned short)hv[1]) * wa.y;
        sum += bf2f((unsigned short)hv[2]) * wa.z;
        sum += bf2f((unsigned short)hv[3]) * wa.w;
        sum += bf2f((unsigned short)hv[4]) * wb.x;
        sum += bf2f((unsigned short)hv[5]) * wb.y;
        sum += bf2f((unsigned short)hv[6]) * wb.z;
        sum += bf2f((unsigned short)hv[7]) * wb.w;
    }
    sum += __shfl_xor(sum, 16);
    sum += __shfl_xor(sum, 32);
    if (kc == 0) {
        float qv = sum + bq[a];
        int av = avail[row * 16 + a];
        if (av == 0) qv -= 1e10f;
        qout[row * 16 + a] = qv;
    }
}

// ---------------------------------------------------------------------------
extern "C" void kernel_launch(void* const* d_in, const int* in_sizes, int n_in,
                              void* d_out, int out_size, void* d_ws, size_t ws_size,
                              hipStream_t stream)
{
    const float* hidden = (const float*)d_in[0];
    const float* x      = (const float*)d_in[1];
    const int*   dones  = (const int*)d_in[2];
    const int*   avail  = (const int*)d_in[3];
    const float* Wl     = (const float*)d_in[4];
    const float* bl     = (const float*)d_in[5];
    const float* ln_g   = (const float*)d_in[6];
    const float* ln_b   = (const float*)d_in[7];
    const float* W_ih   = (const float*)d_in[8];
    const float* W_hh   = (const float*)d_in[9];
    const float* b_ih   = (const float*)d_in[10];
    const float* b_hh   = (const float*)d_in[11];
    const float* Wq     = (const float*)d_in[12];
    const float* bq     = (const float*)d_in[13];

    char* p = (char*)d_ws;
    unsigned short* actA = (unsigned short*)p;                // 16 MB; hst0 after gi GEMM
    unsigned short* hst0 = actA;
    p += (size_t)NROWS * H * 2;
    unsigned short* actB = (unsigned short*)p;                // gi overlays actB+gout (48 MB)
    unsigned short* gi   = actB;
    p += (size_t)NROWS * H * 2;                               // 16 MB
    float* gout = (float*)p; p += (size_t)NROWS * H * 4;      // 32 MB
    unsigned short* rnn  = (unsigned short*)p; p += (size_t)NROWS * H * 2;  // 16 MB
    char* wreg = p;                                           // weights region, 16 MB (hst1 overlay)
    unsigned short* wlb  = (unsigned short*)wreg;             // 2 MB
    unsigned short* wihb = (unsigned short*)(wreg + (size_t)4 * H * H * 2); // 1.5 MB
    unsigned short* hst1 = (unsigned short*)wreg;             // 16 MB (after gi GEMM)
    p += (size_t)NROWS * H * 2;
    int* lenArr = (int*)p;          p += (size_t)NROWS * 4;   // 64 KB
    int* recs   = (int*)p;          p += (size_t)NROWS * 4;   // 64 KB
    unsigned int* meta = (unsigned int*)p;                    // 4 KB
    unsigned int* hist = meta + 16;
    unsigned int* offs = meta + 288;
    int* Marr = (int*)(meta + 560);

    // 1) convert inputs to bf16; zero meta
    cvt_init<<<9984, 256, 0, stream>>>(x, Wl, W_ih, actA, wlb, wihb, meta);

    // 2) segment machinery (needs only dones + meta)
    seg_build<<<64, 256, 0, stream>>>(dones, lenArr, hist);
    seg_offsets<<<1, 256, 0, stream>>>(hist, Marr, offs);
    seg_scatter<<<64, 256, 0, stream>>>(lenArr, offs, recs);

    // 3) MLP stack: 4 x (GEMM f32-out + bias, then LN+ReLU -> bf16)
    unsigned short* cur = actA;
    unsigned short* nxt = actB;
    for (int l = 0; l < 4; ++l) {
        gemm_bt<0><<<512, 256, 0, stream>>>(cur, wlb + (size_t)l * H * H, bl + l * H,
                                            (void*)gout, NROWS, H, H);
        ln_relu<<<4096, 256, 0, stream>>>(gout, ln_g + l * H, ln_b + l * H, nxt);
        unsigned short* tsw = cur; cur = nxt; nxt = tsw;
    }
    // cur == actA

    // 4) gi = act @ W_ih^T + b_ih -> bf16 [NROWS,1536] (overlays actB+gout)
    gemm_bt<1><<<1536, 256, 0, stream>>>(cur, wihb, b_ih, (void*)gi, NROWS, 3 * H, H);

    // 5) init h_state rows (overlays actA, free after gi GEMM)
    h_init<<<4096, 256, 0, stream>>>(recs, Marr, dones, hidden, hst0);

    // 6) segment-parallel GRU scan (persistent, 224 WGs, 1 barrier per local step)
    gru_seg_scan<<<32 * RG, 256, 0, stream>>>(gi, W_hh, b_hh, Marr, recs,
                                              hst0, hst1, rnn, (float*)d_out, meta);

    // 7) Q head + availability mask
    qhead<<<4096, 256, 0, stream>>>(rnn, Wq, bq, avail, (float*)d_out + BATCH * H);
}